// Round 11
// baseline (273.427 us; speedup 1.0000x reference)
//
#include <hip/hip_runtime.h>
#include <math.h>

#define NN 10000
#define HEADS 8
#define NCLS 40
#define CHK 64
#define LOG2E 1.4426950408889634f

typedef __attribute__((ext_vector_type(8))) short short8;
typedef __attribute__((ext_vector_type(4))) float floatx4;

static __device__ __forceinline__ short f2bf(float f) {
    unsigned u = __builtin_bit_cast(unsigned, f);
    unsigned r = (u + 0x7fff + ((u >> 16) & 1)) >> 16;
    return (short)r;
}
static __device__ __forceinline__ float bf2f(unsigned short u) {
    unsigned x = ((unsigned)u) << 16;
    return __builtin_bit_cast(float, x);
}
static __device__ __forceinline__ void gl2lds16(const void* g, void* l) {
    __builtin_amdgcn_global_load_lds(
        (const __attribute__((address_space(1))) unsigned int*)g,
        (__attribute__((address_space(3))) unsigned int*)l, 16, 0, 0);
}

// ---------------- bf16 MFMA GEMM wide: BM=64, BN=128, BK=64, XOR-swizzled LDS ----------
__global__ __launch_bounds__(256) void gemm_bf16_w128(
    const short* __restrict__ A, const short* __restrict__ Bt,
    float* __restrict__ C, short* __restrict__ Cbf,
    float* __restrict__ stats, int M, int Nn, int K, float alpha)
{
    __shared__ short As[64 * 64];
    __shared__ short Bs[128 * 64];
    const int tid = threadIdx.x;
    const int w = tid >> 6, L = tid & 63;
    const int quad = L >> 4, lr = L & 15;
    const int col0 = blockIdx.x * 128, row0 = blockIdx.y * 64;

    const int schunk = (L & 7) ^ (L >> 3);
    const int sarow = w * 16 + (L >> 3);
    int ga0 = row0 + sarow;     if (ga0 > M - 1) ga0 = M - 1;
    int ga1 = row0 + sarow + 8; if (ga1 > M - 1) ga1 = M - 1;
    const short* agp0 = A + (size_t)ga0 * K + schunk * 8;
    const short* agp1 = A + (size_t)ga1 * K + schunk * 8;
    short* alp0 = &As[w * 1024];
    short* alp1 = &As[w * 1024 + 512];
    const int sbrow = w * 32 + (L >> 3);
    int gb[4];
    #pragma unroll
    for (int c = 0; c < 4; c++) {
        gb[c] = col0 + sbrow + c * 8;
        if (gb[c] > Nn - 1) gb[c] = Nn - 1;
    }
    const short* bgp0 = Bt + (size_t)gb[0] * K + schunk * 8;
    const short* bgp1 = Bt + (size_t)gb[1] * K + schunk * 8;
    const short* bgp2 = Bt + (size_t)gb[2] * K + schunk * 8;
    const short* bgp3 = Bt + (size_t)gb[3] * K + schunk * 8;
    short* blp0 = &Bs[w * 2048];
    short* blp1 = &Bs[w * 2048 + 512];
    short* blp2 = &Bs[w * 2048 + 1024];
    short* blp3 = &Bs[w * 2048 + 1536];

    floatx4 acc[4][2];
    const floatx4 zf = {0.f, 0.f, 0.f, 0.f};
    #pragma unroll
    for (int i = 0; i < 4; i++)
        #pragma unroll
        for (int j = 0; j < 2; j++) acc[i][j] = zf;

    for (int k0 = 0; k0 < K; k0 += 64) {
        gl2lds16(agp0 + k0, alp0);
        gl2lds16(agp1 + k0, alp1);
        gl2lds16(bgp0 + k0, blp0);
        gl2lds16(bgp1 + k0, blp1);
        gl2lds16(bgp2 + k0, blp2);
        gl2lds16(bgp3 + k0, blp3);
        __syncthreads();
        #pragma unroll
        for (int ks = 0; ks < 2; ks++) {
            const int sl = ((ks * 4 + quad) ^ (lr & 7)) * 8;
            short8 bfr[2];
            #pragma unroll
            for (int j = 0; j < 2; j++)
                bfr[j] = *(const short8*)&Bs[(w * 32 + j * 16 + lr) * 64 + sl];
            #pragma unroll
            for (int i = 0; i < 4; i++) {
                short8 afr = *(const short8*)&As[(i * 16 + lr) * 64 + sl];
                #pragma unroll
                for (int j = 0; j < 2; j++)
                    acc[i][j] = __builtin_amdgcn_mfma_f32_16x16x32_bf16(afr, bfr[j], acc[i][j], 0, 0, 0);
            }
        }
        __syncthreads();
    }
    float s[2] = {0.f, 0.f}, s2[2] = {0.f, 0.f};
    #pragma unroll
    for (int j = 0; j < 2; j++) {
        int ccol = col0 + w * 32 + j * 16 + lr;
        if (ccol >= Nn) continue;
        #pragma unroll
        for (int i = 0; i < 4; i++) {
            #pragma unroll
            for (int r = 0; r < 4; r++) {
                int crow = row0 + i * 16 + quad * 4 + r;
                if (crow < M) {
                    float v = alpha * acc[i][j][r];
                    if (C)   C[(size_t)crow * Nn + ccol] = v;
                    if (Cbf) Cbf[(size_t)crow * Nn + ccol] = f2bf(v);
                    s[j] += v; s2[j] += v * v;
                }
            }
        }
    }
    if (stats) {
        #pragma unroll
        for (int j = 0; j < 2; j++) {
            s[j]  += __shfl_xor(s[j], 16, 64);  s[j]  += __shfl_xor(s[j], 32, 64);
            s2[j] += __shfl_xor(s2[j], 16, 64); s2[j] += __shfl_xor(s2[j], 32, 64);
        }
        if (L < 16) {
            #pragma unroll
            for (int j = 0; j < 2; j++) {
                int ccol = col0 + w * 32 + j * 16 + L;
                if (ccol < Nn) {
                    atomicAdd(&stats[ccol], s[j]);
                    atomicAdd(&stats[256 + ccol], s2[j]);
                }
            }
        }
    }
}

// ---------------- bf16 MFMA GEMM v3 (BN=64) -- classifier only ----------
__global__ __launch_bounds__(256) void gemm_bf16_v3(
    const short* __restrict__ A, const short* __restrict__ Bt,
    float* __restrict__ C, const float* __restrict__ bias,
    int M, int Nn, int K, float alpha)
{
    __shared__ short As[64 * 64];
    __shared__ short Bs[64 * 64];
    const int tid = threadIdx.x;
    const int w = tid >> 6, L = tid & 63;
    const int quad = L >> 4, lr = L & 15;
    const int col0 = blockIdx.x * 64, row0 = blockIdx.y * 64;

    const int srow = w * 16 + (L >> 3);
    const int schunk = (L & 7) ^ (L >> 3);
    int ga0 = row0 + srow;     if (ga0 > M - 1)  ga0 = M - 1;
    int ga1 = row0 + srow + 8; if (ga1 > M - 1)  ga1 = M - 1;
    int gb0 = col0 + srow;     if (gb0 > Nn - 1) gb0 = Nn - 1;
    int gb1 = col0 + srow + 8; if (gb1 > Nn - 1) gb1 = Nn - 1;
    const short* agp0 = A + (size_t)ga0 * K + schunk * 8;
    const short* agp1 = A + (size_t)ga1 * K + schunk * 8;
    const short* bgp0 = Bt + (size_t)gb0 * K + schunk * 8;
    const short* bgp1 = Bt + (size_t)gb1 * K + schunk * 8;
    short* alp0 = &As[w * 1024];
    short* alp1 = &As[w * 1024 + 512];
    short* blp0 = &Bs[w * 1024];
    short* blp1 = &Bs[w * 1024 + 512];

    floatx4 acc[4];
    const floatx4 zf = {0.f, 0.f, 0.f, 0.f};
    #pragma unroll
    for (int i = 0; i < 4; i++) acc[i] = zf;

    for (int k0 = 0; k0 < K; k0 += 64) {
        gl2lds16(agp0 + k0, alp0);
        gl2lds16(agp1 + k0, alp1);
        gl2lds16(bgp0 + k0, blp0);
        gl2lds16(bgp1 + k0, blp1);
        __syncthreads();
        #pragma unroll
        for (int ks = 0; ks < 2; ks++) {
            const int sl = ((ks * 4 + quad) ^ (lr & 7)) * 8;
            short8 bfr = *(const short8*)&Bs[(w * 16 + lr) * 64 + sl];
            #pragma unroll
            for (int i = 0; i < 4; i++) {
                short8 afr = *(const short8*)&As[(i * 16 + lr) * 64 + sl];
                acc[i] = __builtin_amdgcn_mfma_f32_16x16x32_bf16(afr, bfr, acc[i], 0, 0, 0);
            }
        }
        __syncthreads();
    }
    const int ccol = col0 + w * 16 + lr;
    if (ccol < Nn) {
        float bv = bias ? bias[ccol] : 0.f;
        #pragma unroll
        for (int i = 0; i < 4; i++) {
            #pragma unroll
            for (int r = 0; r < 4; r++) {
                int crow = row0 + i * 16 + quad * 4 + r;
                if (crow < M) C[(size_t)crow * Nn + ccol] = alpha * acc[i][r] + bv;
            }
        }
    }
}

// ---------------- CSR build ----------------
__global__ __launch_bounds__(1024) void scan_kernel(
    int* counts, int* offsets, int* cursor, int* elist, int n)
{
    const int P = (n + 1023) >> 10;
    __shared__ int wsum[16];
    int tid = threadIdx.x, lane = tid & 63, wid = tid >> 6;
    int base = tid * P;
    int local[16];
    int deg[16];
    int s = 0;
    for (int j = 0; j < P; j++) {
        int i = base + j;
        local[j] = s;
        deg[j] = (i < n) ? counts[i] + 1 : 0;   // +1 self-loop
        s += deg[j];
    }
    int inc = s;
    #pragma unroll
    for (int off = 1; off < 64; off <<= 1) {
        int tv = __shfl_up(inc, off, 64);
        if (lane >= off) inc += tv;
    }
    if (lane == 63) wsum[wid] = inc;
    __syncthreads();
    if (tid < 16) {
        int v = wsum[tid];
        int winc = v;
        #pragma unroll
        for (int off = 1; off < 16; off <<= 1) {
            int tv = __shfl_up(winc, off, 16);
            if (tid >= off) winc += tv;
        }
        wsum[tid] = winc - v;
    }
    __syncthreads();
    int excl = inc - s + wsum[wid];
    for (int j = 0; j < P; j++) {
        int i = base + j;
        if (i < n) {
            int o = excl + local[j];
            counts[i] = deg[j];
            offsets[i] = o;
            elist[o] = i;       // self-loop in slot 0
            cursor[i] = o + 1;
        }
    }
}

__global__ void scatter_edges_kernel(const int* __restrict__ src, const int* __restrict__ dst,
                                     int* cursor, int* elist, int E) {
    int e = blockIdx.x * 256 + threadIdx.x;
    if (e < E) {
        int d = dst[e];
        int pos = atomicAdd(&cursor[d], 1);
        elist[pos] = src[e];
    }
}

// ---------------- all weight/input prep + edge counting in one launch ----------------
__global__ __launch_bounds__(256) void prep_count(
    const float* __restrict__ x, const float* __restrict__ W0,
    const float* __restrict__ W1, const float* __restrict__ a_src1,
    const float* __restrict__ a_dst1, const float* __restrict__ Wc,
    const int* __restrict__ edst, int E,
    short* __restrict__ xb, short* __restrict__ W0T, float* __restrict__ v1,
    short* __restrict__ W1pT, short* __restrict__ WcT, int* __restrict__ counts)
{
    __shared__ float tile[32][33];
    const int b = blockIdx.x, t = threadIdx.x;
    if (b < 2500) {
        int i = b * 256 + t;
        floatx4 v = ((const floatx4*)x)[i];
        short4 o = {f2bf(v[0]), f2bf(v[1]), f2bf(v[2]), f2bf(v[3])};
        ((short4*)xb)[i] = o;
    } else if (b < 2756) {
        int o = b - 2500;
        W0T[o * 256 + t] = f2bf(W0[t * 256 + o]);
    } else if (b < 2772) {
        int idx = (b - 2756) * 256 + t;
        int f = idx >> 4, j = idx & 15;
        int h = j & 7;
        const float* a = (j < 8) ? a_src1 : a_dst1;
        float s = 0.f;
        for (int c = 0; c < 256; c++)
            s += W1[f * 2048 + h * 256 + c] * a[h * 256 + c];
        v1[idx] = s;
    } else if (b < 3284) {
        int id = b - 2772;
        int h = id >> 6, f0 = ((id >> 3) & 7) * 32, c0 = (id & 7) * 32;
        int tx = t & 31, ty = t >> 5;
        for (int r = ty; r < 32; r += 8)
            tile[r][tx] = W1[(size_t)(f0 + r) * 2048 + h * 256 + c0 + tx];
        __syncthreads();
        for (int r = ty; r < 32; r += 8)
            W1pT[(size_t)(c0 + r) * 2048 + h * 256 + f0 + tx] = f2bf(tile[tx][r]);
    } else if (b < 3324) {
        int o = b - 3284;
        WcT[o * 256 + t] = f2bf(Wc[t * 40 + o]);
    } else {
        int e = (b - 3324) * 256 + t;
        if (e < E) atomicAdd(&counts[edst[e]], 1);
    }
}

// ---------------- layer-0 node scores: wave per node ----------------
__global__ __launch_bounds__(256) void score0_wave(
    const unsigned short* __restrict__ h0b, const float* __restrict__ a_src,
    const float* __restrict__ a_dst, float* __restrict__ s0)
{
    const int wid = threadIdx.x >> 6, L = threadIdx.x & 63;
    const int n = blockIdx.x * 4 + wid;   // NN % 4 == 0
    ushort4 vv = *(const ushort4*)(h0b + (size_t)n * 256 + 4 * L);
    floatx4 as = *(const floatx4*)(a_src + 4 * L);
    floatx4 ad = *(const floatx4*)(a_dst + 4 * L);
    float v0 = bf2f(vv.x), v1_ = bf2f(vv.y), v2 = bf2f(vv.z), v3 = bf2f(vv.w);
    float ps = v0 * as[0] + v1_ * as[1] + v2 * as[2] + v3 * as[3];
    float pd = v0 * ad[0] + v1_ * ad[1] + v2 * ad[2] + v3 * ad[3];
    #pragma unroll
    for (int off = 1; off < 8; off <<= 1) {
        ps += __shfl_xor(ps, off, 64);
        pd += __shfl_xor(pd, off, 64);
    }
    if ((L & 7) == 0) {
        s0[n * 16 + (L >> 3)] = ps;
        s0[n * 16 + 8 + (L >> 3)] = pd;
    }
}

// ---------------- fused softmax(no-max)+aggregate, layer 0 (4x unrolled gather) --------
__global__ __launch_bounds__(256) void agg0_fused(
    const unsigned short* __restrict__ h0b, const float* __restrict__ s0,
    const int* __restrict__ offsets, const int* __restrict__ counts,
    const int* __restrict__ elist, float* __restrict__ out)
{
    __shared__ float pw_s[4][CHK * 8];
    __shared__ int   sn_s[4][CHK];
    const int wid = threadIdx.x >> 6, L = threadIdx.x & 63;
    const int n = blockIdx.x * 4 + wid;   // NN % 4 == 0
    float* pw = pw_s[wid];
    int*   sw = sn_s[wid];
    const int deg = counts[n], start = offsets[n];
    const int hL = L >> 3;

    floatx4 sda = *(const floatx4*)(s0 + n * 16 + 8);
    floatx4 sdb = *(const floatx4*)(s0 + n * 16 + 12);
    float sd[8] = {sda[0], sda[1], sda[2], sda[3], sdb[0], sdb[1], sdb[2], sdb[3]};
    float lp[8] = {0.f, 0.f, 0.f, 0.f, 0.f, 0.f, 0.f, 0.f};
    float a0 = 0.f, a1 = 0.f, a2 = 0.f, a3 = 0.f;

    for (int e0 = 0; e0 < deg; e0 += CHK) {
        int ch = deg - e0; if (ch > CHK) ch = CHK;
        if (L < ch) {
            int sn = elist[start + e0 + L];
            sw[L] = sn;
            floatx4 ssa = *(const floatx4*)(s0 + sn * 16);
            floatx4 ssb = *(const floatx4*)(s0 + sn * 16 + 4);
            float ss[8] = {ssa[0], ssa[1], ssa[2], ssa[3], ssb[0], ssb[1], ssb[2], ssb[3]};
            float p[8];
            #pragma unroll
            for (int h = 0; h < 8; h++) {
                float v = ss[h] + sd[h];
                v = (v > 0.f) ? v : 0.2f * v;
                p[h] = exp2f(v * LOG2E);
                lp[h] += p[h];
            }
            floatx4 p0 = {p[0], p[1], p[2], p[3]};
            floatx4 p1 = {p[4], p[5], p[6], p[7]};
            *(floatx4*)&pw[L * 8] = p0;
            *(floatx4*)&pw[L * 8 + 4] = p1;
        }
        // 4x-unrolled gather: 4 independent L2 loads in flight per iteration
        int e = 0;
        for (; e + 4 <= ch; e += 4) {
            int4 sn4 = *(const int4*)&sw[e];
            float w0 = pw[(e + 0) * 8 + hL];
            float w1 = pw[(e + 1) * 8 + hL];
            float w2 = pw[(e + 2) * 8 + hL];
            float w3 = pw[(e + 3) * 8 + hL];
            ushort4 va = *(const ushort4*)(h0b + (size_t)sn4.x * 256 + 4 * L);
            ushort4 vb = *(const ushort4*)(h0b + (size_t)sn4.y * 256 + 4 * L);
            ushort4 vc = *(const ushort4*)(h0b + (size_t)sn4.z * 256 + 4 * L);
            ushort4 vd = *(const ushort4*)(h0b + (size_t)sn4.w * 256 + 4 * L);
            a0 += w0 * bf2f(va.x) + w1 * bf2f(vb.x) + w2 * bf2f(vc.x) + w3 * bf2f(vd.x);
            a1 += w0 * bf2f(va.y) + w1 * bf2f(vb.y) + w2 * bf2f(vc.y) + w3 * bf2f(vd.y);
            a2 += w0 * bf2f(va.z) + w1 * bf2f(vb.z) + w2 * bf2f(vc.z) + w3 * bf2f(vd.z);
            a3 += w0 * bf2f(va.w) + w1 * bf2f(vb.w) + w2 * bf2f(vc.w) + w3 * bf2f(vd.w);
        }
        for (; e < ch; e++) {
            float wgt = pw[e * 8 + hL];
            ushort4 vv = *(const ushort4*)(h0b + (size_t)sw[e] * 256 + 4 * L);
            a0 += wgt * bf2f(vv.x);
            a1 += wgt * bf2f(vv.y);
            a2 += wgt * bf2f(vv.z);
            a3 += wgt * bf2f(vv.w);
        }
    }
    #pragma unroll
    for (int off = 1; off < 64; off <<= 1)
        #pragma unroll
        for (int h = 0; h < 8; h++)
            lp[h] += __shfl_xor(lp[h], off, 64);
    float inv = 1.f / lp[hL];
    floatx4 o = {a0 * inv, a1 * inv, a2 * inv, a3 * inv};
    *(floatx4*)(out + (size_t)n * 256 + 4 * L) = o;
}

// ---------------- layer-1 aggregate: 2 waves/node, 4 heads each, 4x unrolled gather ----
__global__ __launch_bounds__(256) void agg1_half(
    const unsigned short* __restrict__ hb, const float* __restrict__ s1,
    const int* __restrict__ offsets, const int* __restrict__ counts,
    const int* __restrict__ elist, short* __restrict__ aggout)
{
    __shared__ float pw_s[4][CHK * 4];
    __shared__ int   sn_s[4][CHK];
    const int wid = threadIdx.x >> 6, L = threadIdx.x & 63;
    const int n = blockIdx.x * 2 + (wid >> 1);   // NN % 2 == 0
    const int hg = wid & 1;
    float* pw = pw_s[wid];
    int*   sw = sn_s[wid];
    const int deg = counts[n], start = offsets[n];

    floatx4 sd4 = *(const floatx4*)(s1 + n * 16 + 8 + hg * 4);
    float lp[4] = {0.f, 0.f, 0.f, 0.f};
    float acc[4][4];
    #pragma unroll
    for (int h = 0; h < 4; h++)
        #pragma unroll
        for (int f = 0; f < 4; f++) acc[h][f] = 0.f;

    for (int e0 = 0; e0 < deg; e0 += CHK) {
        int ch = deg - e0; if (ch > CHK) ch = CHK;
        if (L < ch) {
            int sn = elist[start + e0 + L];
            sw[L] = sn;
            floatx4 ss4 = *(const floatx4*)(s1 + sn * 16 + hg * 4);
            floatx4 p4;
            #pragma unroll
            for (int h = 0; h < 4; h++) {
                float v = ss4[h] + sd4[h];
                v = (v > 0.f) ? v : 0.2f * v;
                float p = exp2f(v * LOG2E);
                p4[h] = p;
                lp[h] += p;
            }
            *(floatx4*)&pw[L * 4] = p4;
        }
        // 4x-unrolled gather
        int e = 0;
        for (; e + 4 <= ch; e += 4) {
            int4 sn4 = *(const int4*)&sw[e];
            floatx4 pva = *(const floatx4*)&pw[(e + 0) * 4];
            floatx4 pvb = *(const floatx4*)&pw[(e + 1) * 4];
            floatx4 pvc = *(const floatx4*)&pw[(e + 2) * 4];
            floatx4 pvd = *(const floatx4*)&pw[(e + 3) * 4];
            ushort4 va = *(const ushort4*)(hb + (size_t)sn4.x * 256 + 4 * L);
            ushort4 vb = *(const ushort4*)(hb + (size_t)sn4.y * 256 + 4 * L);
            ushort4 vc = *(const ushort4*)(hb + (size_t)sn4.z * 256 + 4 * L);
            ushort4 vd = *(const ushort4*)(hb + (size_t)sn4.w * 256 + 4 * L);
            float a0 = bf2f(va.x), a1 = bf2f(va.y), a2 = bf2f(va.z), a3 = bf2f(va.w);
            float b0 = bf2f(vb.x), b1 = bf2f(vb.y), b2 = bf2f(vb.z), b3 = bf2f(vb.w);
            float c0 = bf2f(vc.x), c1 = bf2f(vc.y), c2 = bf2f(vc.z), c3 = bf2f(vc.w);
            float d0 = bf2f(vd.x), d1 = bf2f(vd.y), d2 = bf2f(vd.z), d3 = bf2f(vd.w);
            #pragma unroll
            for (int h = 0; h < 4; h++) {
                acc[h][0] += pva[h] * a0 + pvb[h] * b0 + pvc[h] * c0 + pvd[h] * d0;
                acc[h][1] += pva[h] * a1 + pvb[h] * b1 + pvc[h] * c1 + pvd[h] * d1;
                acc[h][2] += pva[h] * a2 + pvb[h] * b2 + pvc[h] * c2 + pvd[h] * d2;
                acc[h][3] += pva[h] * a3 + pvb[h] * b3 + pvc[h] * c3 + pvd[h] * d3;
            }
        }
        for (; e < ch; e++) {
            floatx4 pv = *(const floatx4*)&pw[e * 4];
            ushort4 vv = *(const ushort4*)(hb + (size_t)sw[e] * 256 + 4 * L);
            float v0 = bf2f(vv.x), v1_ = bf2f(vv.y), v2 = bf2f(vv.z), v3 = bf2f(vv.w);
            #pragma unroll
            for (int h = 0; h < 4; h++) {
                acc[h][0] += pv[h] * v0;
                acc[h][1] += pv[h] * v1_;
                acc[h][2] += pv[h] * v2;
                acc[h][3] += pv[h] * v3;
            }
        }
    }
    #pragma unroll
    for (int off = 1; off < 64; off <<= 1)
        #pragma unroll
        for (int h = 0; h < 4; h++)
            lp[h] += __shfl_xor(lp[h], off, 64);
    #pragma unroll
    for (int h = 0; h < 4; h++) {
        float inv = 1.f / lp[h];
        short4 o = {f2bf(acc[h][0] * inv), f2bf(acc[h][1] * inv),
                    f2bf(acc[h][2] * inv), f2bf(acc[h][3] * inv)};
        *(short4*)(aggout + (size_t)n * 2048 + (hg * 4 + h) * 256 + 4 * L) = o;
    }
}

// ---------------- batchnorm stats ----------------
__global__ __launch_bounds__(256) void bn_stats_kernel(const float* __restrict__ x, float* stats, int n) {
    int t = threadIdx.x;
    float s = 0.f, s2 = 0.f;
    for (int r = blockIdx.x; r < n; r += gridDim.x) {
        float v = x[(size_t)r * 256 + t];
        s += v; s2 += v * v;
    }
    atomicAdd(&stats[t], s);
    atomicAdd(&stats[256 + t], s2);
}

// ---------------- BN + ELU + bf16 write + layer-1 score, one block per node ------------
__global__ __launch_bounds__(256) void bnapply_score1(
    const float* __restrict__ xg, const float* __restrict__ stats,
    const float* __restrict__ g, const float* __restrict__ be,
    const float* __restrict__ v1, short* __restrict__ hactb, float* __restrict__ s1)
{
    __shared__ float row[256];
    __shared__ float part[16][17];
    const int n = blockIdx.x, t = threadIdx.x;
    const float invN = 1.0f / NN;
    float mu = stats[t] * invN;
    float var = stats[256 + t] * invN - mu * mu;
    float v = g[t] * (xg[(size_t)n * 256 + t] - mu) * rsqrtf(var + 1e-5f) + be[t];
    v = (v > 0.f) ? v : (expf(v) - 1.f);   // ELU
    hactb[(size_t)n * 256 + t] = f2bf(v);
    row[t] = v;
    __syncthreads();
    int j = t & 15, f0 = t >> 4;
    float p = 0.f;
    #pragma unroll
    for (int k = 0; k < 16; k++)
        p += row[f0 * 16 + k] * v1[(f0 * 16 + k) * 16 + j];
    part[f0][j] = p;
    __syncthreads();
    if (t < 16) {
        float s = 0.f;
        #pragma unroll
        for (int k = 0; k < 16; k++) s += part[k][t];
        s1[n * 16 + t] = s;
    }
}

// ---------------- BN + ELU + residual (bf16) -> bf16, elementwise ----------------
__global__ __launch_bounds__(256) void bn_apply_kernel(
    const float* __restrict__ x, const float* __restrict__ stats,
    const float* __restrict__ g, const float* __restrict__ be,
    const unsigned short* __restrict__ resid, short* __restrict__ ybf, int total)
{
    int i = blockIdx.x * 256 + threadIdx.x;
    if (i >= total) return;
    int c = i & 255;
    const float invN = 1.0f / NN;
    float mu = stats[c] * invN;
    float var = stats[256 + c] * invN - mu * mu;
    float v = g[c] * (x[i] - mu) * rsqrtf(var + 1e-5f) + be[c];
    v = (v > 0.f) ? v : (expf(v) - 1.f);   // ELU
    v += bf2f(resid[i]);
    ybf[i] = f2bf(v);
}

// ---------------- launch ----------------
extern "C" void kernel_launch(void* const* d_in, const int* in_sizes, int n_in,
                              void* d_out, int out_size, void* d_ws, size_t ws_size,
                              hipStream_t stream) {
    const float* x      = (const float*)d_in[0];
    const int*   eidx   = (const int*)d_in[1];
    const float* W0     = (const float*)d_in[2];
    const float* a_src0 = (const float*)d_in[3];
    const float* a_dst0 = (const float*)d_in[4];
    const float* g0     = (const float*)d_in[6];
    const float* be0    = (const float*)d_in[7];
    const float* W1     = (const float*)d_in[8];
    const float* a_src1 = (const float*)d_in[9];
    const float* a_dst1 = (const float*)d_in[10];
    const float* g1     = (const float*)d_in[12];
    const float* be1    = (const float*)d_in[13];
    const float* Wc     = (const float*)d_in[14];
    const float* bc     = (const float*)d_in[15];
    float* out = (float*)d_out;

    const int E = in_sizes[1] / 2;
    const int* esrc = eidx;
    const int* edst = eidx + E;

    char* ws = (char*)d_ws;
    size_t off = 0;
    auto alloc = [&](size_t bytes) {
        void* p = ws + off;
        off += (bytes + 255) & ~(size_t)255;
        return p;
    };
    float* stats   = (float*)alloc(1024 * 4);
    int*   counts  = (int*)alloc(NN * 4);
    float* out1    = (float*)alloc((size_t)NN * 256 * 4);
    short* h0b     = (short*)alloc((size_t)NN * 256 * 2);
    short* xb      = (short*)alloc((size_t)NN * 256 * 2);
    float* s0      = (float*)alloc((size_t)NN * 16 * 4);
    float* s1      = (float*)alloc((size_t)NN * 16 * 4);
    float* v1      = (float*)alloc(4096 * 4);
    float* h_gat0  = (float*)alloc((size_t)NN * 256 * 4);
    short* hactb   = (short*)alloc((size_t)NN * 256 * 2);
    short* agg1bf  = (short*)alloc((size_t)NN * 2048 * 2);
    short* W0T     = (short*)alloc((size_t)256 * 256 * 2);
    short* W1pT    = (short*)alloc((size_t)256 * 2048 * 2);
    short* WcT     = (short*)alloc((size_t)64 * 256 * 2);
    short* hfinbf  = (short*)alloc((size_t)NN * 256 * 2);
    int* offsets   = (int*)alloc((NN + 16) * 4);
    int* cursor    = (int*)alloc(NN * 4);
    int* elist     = (int*)alloc((size_t)(E + NN) * 4);

    float* stats0 = stats;
    float* stats1 = stats + 512;

    hipMemsetAsync(stats, 0, 1024 * 4 + NN * 4, stream);   // stats0+stats1+counts

    const int cntBlocks = (E + 255) / 256;
    prep_count<<<3324 + cntBlocks, 256, 0, stream>>>(
        x, W0, W1, a_src1, a_dst1, Wc, edst, E,
        xb, W0T, v1, W1pT, WcT, counts);

    scan_kernel<<<1, 1024, 0, stream>>>(counts, offsets, cursor, elist, NN);
    scatter_edges_kernel<<<cntBlocks, 256, 0, stream>>>(esrc, edst, cursor, elist, E);

    // layer 0
    {
        dim3 grid(2, (NN + 63) / 64);
        gemm_bf16_w128<<<grid, 256, 0, stream>>>(xb, W0T, nullptr, h0b, nullptr,
                                                 NN, 256, 256, 1.0f);
    }
    score0_wave<<<NN / 4, 256, 0, stream>>>(
        (const unsigned short*)h0b, a_src0, a_dst0, s0);
    agg0_fused<<<NN / 4, 256, 0, stream>>>(
        (const unsigned short*)h0b, s0, offsets, counts, elist, h_gat0);
    bn_stats_kernel<<<256, 256, 0, stream>>>(h_gat0, stats0, NN);
    bnapply_score1<<<NN, 256, 0, stream>>>(h_gat0, stats0, g0, be0, v1, hactb, s1);

    // layer 1
    agg1_half<<<NN / 2, 256, 0, stream>>>(
        (const unsigned short*)hactb, s1, offsets, counts, elist, agg1bf);
    {
        dim3 grid(2, (NN + 63) / 64);
        gemm_bf16_w128<<<grid, 256, 0, stream>>>(agg1bf, W1pT, out1, nullptr, stats1,
                                                 NN, 256, 2048, 0.125f);
    }
    bn_apply_kernel<<<(NN * 256 + 255) / 256, 256, 0, stream>>>(
        out1, stats1, g1, be1, (const unsigned short*)hactb, hfinbf, NN * 256);

    // classifier (bf16 MFMA, BN=64)
    {
        dim3 grid(1, (NN + 63) / 64);
        gemm_bf16_v3<<<grid, 256, 0, stream>>>(hfinbf, WcT, out, bc,
                                               NN, NCLS, 256, 1.0f);
    }
}